// Round 9
// baseline (74.981 us; speedup 1.0000x reference)
//
#include <hip/hip_runtime.h>

// Reck-mesh MZI layer, N=256, BATCH=4096.
// out[b][i] = sum_j x[b][j] * Re(e^{i phi_ext[i]} U[i][j])
// Depth-split: U = A * B, A = steps 256..511 applied to I, B = steps 0..255.
// 512 independent half-depth column chains (wavefront t = 2L+p, disjoint row
// pairs per step). 8 column-waves per block (2/SIMD fills single-wave issue
// gaps); each wave also stages 2 of 16 ring slots (global->reg->ds_write,
// R8-proven ordering). Raw s_barrier + lgkmcnt(0); global loads uncounted.
// Merge kernel: W^T[j][i] = Re(e^{i phi_i} sum_k A[i][k] B[k][j]), then GEMM.

#define NN 256
#define NB 4096

typedef float f32x4 __attribute__((ext_vector_type(4)));

// ws layout:
//  [0, 1MB)       cf3: 64 groups x 16 slots x 64 lanes x 16B
//  [1MB, 1.5MB)   A  float2[256][256]  (steps 256..511)
//  [1.5MB, 2MB)   B  float2[256][256]  (steps 0..255)
//  [2MB, 2.25MB)  Wt float[256][256]   (Wt[j][i])
#define WS_A_OFF  (1u << 20)
#define WS_B_OFF  ((1u << 20) + (1u << 19))
#define WS_WT_OFF (1u << 21)

// ---------------- coefficient stream ----------------
// t = 8g + jj. slot A_jj = jj (p = 4l, +1 if t odd), slot B_jj = 8+jj (p = A+2).
// Identity (1,0,0) baked in for inactive ops (incl. pad steps t=509..511).
__global__ __launch_bounds__(64) void coeff2_kernel(const float* __restrict__ theta,
                                                    const float* __restrict__ phi,
                                                    f32x4* __restrict__ cf3) {
    const int t = blockIdx.x;        // 0..511
    const int l = threadIdx.x;
    const int g = t >> 3, jj = t & 7;
    const int pA = (t & 1) ? (4 * l + 1) : (4 * l);
#pragma unroll
    for (int s = 0; s < 2; ++s) {
        int p = pA + 2 * s;
        f32x4 v = {1.f, 0.f, 0.f, 0.f};              // identity rotation
        if (p <= t && p + t <= 508) {                // active op at (t,p)
            int L = (t - p) >> 1;                    // layer 0..254
            int k = ((L * (511 - L)) >> 1) + p;      // off(L) = L*(511-L)/2
            float st, ct, sp, cp;
            __sincosf(theta[k], &st, &ct);
            __sincosf(phi[k], &sp, &cp);
            v = (f32x4){ct, st * cp, st * sp, 0.f};
        }
        cf3[(g * 16 + 8 * s + jj) * 64 + l] = v;
    }
}

// ---------------- build A/B columns ----------------
__device__ __forceinline__ float dpp_up1(float x) {   // lane i <- lane i-1, lane0 -> 0
    int r = __builtin_amdgcn_update_dpp(0, __builtin_bit_cast(int, x), 0x138, 0xF, 0xF, true);
    return __builtin_bit_cast(float, r);
}
__device__ __forceinline__ float dpp_dn1(float x) {   // lane i <- lane i+1, lane63 -> 0
    int r = __builtin_amdgcn_update_dpp(0, __builtin_bit_cast(int, x), 0x130, 0xF, 0xF, true);
    return __builtin_bit_cast(float, r);
}

__device__ __forceinline__ void rot2(float& ar, float& ai, float& br, float& bi, f32x4 co) {
    float c = co.x, sx = co.y, sy = co.z;
    float nar = c * ar - (sx * br + sy * bi);
    float nai = c * ai - (sx * bi - sy * br);
    float nbr = sx * ar - sy * ai + c * br;
    float nbi = sx * ai + sy * ar + c * bi;
    ar = nar; ai = nai; br = nbr; bi = nbi;
}

// LDS-only barrier: drain LDS ops; global loads may stay in flight.
__device__ __forceinline__ void softbar() {
    __builtin_amdgcn_sched_barrier(0);
    asm volatile("s_waitcnt lgkmcnt(0)" ::: "memory");
    __builtin_amdgcn_s_barrier();
    __builtin_amdgcn_sched_barrier(0);
}

__global__ __launch_bounds__(512, 1) void build_kernel(const f32x4* __restrict__ cf3,
                                                       float2* __restrict__ Aout,
                                                       float2* __restrict__ Bout) {
    // ring: 4 groups x 16 slots x 64 lanes x 16B = 65,536 B
    __shared__ f32x4 ring[4 * 16 * 64];

    const int tid = threadIdx.x;
    const int wid = tid >> 6;            // 0..7: column-wave index
    const int l   = tid & 63;
    const int r0  = 4 * l;
    const int j   = blockIdx.x * 8 + wid;   // column of the half-product
    const int h   = blockIdx.y;             // 0: steps 0..255 (B), 1: 256..511 (A)
    const int G0  = 32 * h;                  // first group of this half
    float2* dst = h ? Aout : Bout;

    // state: rows 4l..4l+3 of column j, initialized to identity column
    float ur0 = (r0 + 0 == j) ? 1.f : 0.f, ui0 = 0.f;
    float ur1 = (r0 + 1 == j) ? 1.f : 0.f, ui1 = 0.f;
    float ur2 = (r0 + 2 == j) ? 1.f : 0.f, ui2 = 0.f;
    float ur3 = (r0 + 3 == j) ? 1.f : 0.f, ui3 = 0.f;
    const float lane0_one = (l == 0) ? 1.f : 0.f;   // C.x identity fix at lane 0

    f32x4 SA[2], SB[2];     // staging ping-pong (this wave's 2 slots)
    f32x4 RA[16], RB[16];   // consume ping-pong

    auto loadgrp2 = [&](int g, f32x4 (&S)[2]) {      // global -> reg, 2 slots
        const f32x4* sp = cf3 + (size_t)g * 1024 + l;
        S[0] = sp[(2 * wid) * 64];
        S[1] = sp[(2 * wid + 1) * 64];
    };
    auto writeslot2 = [&](int slot, const f32x4 (&S)[2]) {   // reg -> LDS
        f32x4* dp = ring + slot * 1024 + l;
        dp[(2 * wid) * 64]     = S[0];
        dp[(2 * wid + 1) * 64] = S[1];
    };
    auto readslot = [&](int slot, f32x4 (&R)[16]) {
        const f32x4* rp = ring + slot * 1024 + l;
#pragma unroll
        for (int s = 0; s < 16; ++s) R[s] = rp[s * 64];
    };

    auto compute = [&](const f32x4 (&R)[16]) {       // 8 steps, VALU+DPP only
#pragma unroll
        for (int jj = 0; jj < 8; ++jj) {
            if ((jj & 1) == 0) {
                rot2(ur0, ui0, ur1, ui1, R[jj]);        // p = 4l
                rot2(ur2, ui2, ur3, ui3, R[8 + jj]);    // p = 4l+2
            } else {
                float d0r = dpp_dn1(ur0), d0i = dpp_dn1(ui0);  // lane l+1 row 4l+4
                float u3r = dpp_up1(ur3), u3i = dpp_up1(ui3);  // lane l-1 row 4l-1
                f32x4 cb = R[8 + jj];
                float cx = dpp_up1(cb.x) + lane0_one;   // C = lane l-1's B (lane0: id)
                float cy = dpp_up1(cb.y);
                float cz = dpp_up1(cb.z);
                rot2(ur1, ui1, ur2, ui2, R[jj]);        // p = 4l+1
                // p = 4l+3 (upper half here; lane63's B is identity)
                float n3r = cb.x * ur3 - (cb.y * d0r + cb.z * d0i);
                float n3i = cb.x * ui3 - (cb.y * d0i - cb.z * d0r);
                // p = 4l-1 (lower half here; lane0's C is identity)
                float n0r = cy * u3r - cz * u3i + cx * ur0;
                float n0i = cy * u3i + cz * u3r + cx * ui0;
                ur3 = n3r; ui3 = n3i; ur0 = n0r; ui0 = n0i;
            }
        }
    };

    // prefill: stage groups 0,1 into slots 0,1; hold groups 2,3 in regs
    loadgrp2(G0 + 0, SA);
    loadgrp2(G0 + 1, SB);
    writeslot2(0, SA);
    loadgrp2(G0 + 2, SA);
    writeslot2(1, SB);
    loadgrp2(G0 + 3, SB);
    softbar();
    readslot(0, RA);

    // 32 intervals (unrolled x2 for static ping-pong)
    for (int g2 = 0; g2 < 32; g2 += 2) {
        // interval g2: stage group g2+2 (slot), load g2+4; compute group g2
        if (g2 + 2 < 32) writeslot2((g2 + 2) & 3, SA);   // SA loaded 2 intervals ago
        if (g2 + 4 < 32) loadgrp2(G0 + g2 + 4, SA);      // refill after store
        if (g2 + 1 < 32) readslot((g2 + 1) & 3, RB);
        compute(RA);
        softbar();
        // interval g2+1
        if (g2 + 3 < 32) writeslot2((g2 + 3) & 3, SB);
        if (g2 + 5 < 32) loadgrp2(G0 + g2 + 5, SB);
        if (g2 + 2 < 32) readslot((g2 + 2) & 3, RA);
        compute(RB);
        softbar();
    }

    // store half-product column j (no phase here)
    dst[(r0 + 0) * NN + j] = make_float2(ur0, ui0);
    dst[(r0 + 1) * NN + j] = make_float2(ur1, ui1);
    dst[(r0 + 2) * NN + j] = make_float2(ur2, ui2);
    dst[(r0 + 3) * NN + j] = make_float2(ur3, ui3);
}

// ---------------- merge: Wt[j][i] = Re(e^{i phi_i} sum_k A[i][k] B[k][j]) ----
// grid (16,16), 256 thr; 16(i) x 16(j) tile, K staged in chunks of 64.
__global__ __launch_bounds__(256) void merge_kernel(const float2* __restrict__ A,
                                                    const float2* __restrict__ B,
                                                    const float* __restrict__ phi_ext,
                                                    float* __restrict__ Wt) {
    __shared__ float2 As[64][16];   // [k][i]
    __shared__ float2 Bs[64][17];   // [k][j] (+1 pad: conflict-free staging writes)

    const int t  = threadIdx.x;
    const int i0 = blockIdx.x * 16;
    const int j0 = blockIdx.y * 16;
    const int ti = t & 15;
    const int tj = t >> 4;

    float wr = 0.f, wi = 0.f;

    for (int kc = 0; kc < NN; kc += 64) {
        // stage A[i0..+16)[kc..+64) -> As[k][i]  (2 cplx per thread per rep)
#pragma unroll
        for (int rep = 0; rep < 2; ++rep) {
            int e = t + rep * 256;
            int ai = e & 15, kq = e >> 4;            // kq 0..31
            float4 v = *(const float4*)(A + (size_t)(i0 + ai) * NN + kc + 2 * kq);
            As[2 * kq + 0][ai] = make_float2(v.x, v.y);
            As[2 * kq + 1][ai] = make_float2(v.z, v.w);
        }
        // stage B[kc..+64)[j0..+16) -> Bs[k][j]
#pragma unroll
        for (int rep = 0; rep < 2; ++rep) {
            int e = t + rep * 256;
            int r = e >> 3, q = e & 7;               // r 0..63, q 0..7
            float4 v = *(const float4*)(B + (size_t)(kc + r) * NN + j0 + 2 * q);
            Bs[r][2 * q + 0] = make_float2(v.x, v.y);
            Bs[r][2 * q + 1] = make_float2(v.z, v.w);
        }
        __syncthreads();
#pragma unroll 8
        for (int k = 0; k < 64; ++k) {
            float2 a = As[k][ti];
            float2 b = Bs[k][tj];
            wr += a.x * b.x - a.y * b.y;
            wi += a.x * b.y + a.y * b.x;
        }
        __syncthreads();
    }

    float sp, cp;
    __sincosf(phi_ext[i0 + ti], &sp, &cp);
    Wt[(size_t)(j0 + tj) * NN + i0 + ti] = cp * wr - sp * wi;
}

// ---------------- out = x @ Wt (fp32; no fp32 MFMA on CDNA4) ----------------
__global__ __launch_bounds__(256) void gemm_kernel(const float* __restrict__ x,
                                                   const float* __restrict__ Wt,
                                                   float* __restrict__ out) {
    __shared__ float Xs[64][36];
    __shared__ float Bs[32][68];

    const int tid = threadIdx.x;
    const int b0 = blockIdx.x * 64;
    const int i0 = blockIdx.y * 64;
    const int tx = tid & 15;
    const int ty = tid >> 4;

    const int xr = tid >> 3;
    const int xc = (tid & 7) * 4;
    const int bk = tid >> 4;
    const int bc = (tid & 15) * 4;

    float acc[4][4] = {};

    for (int k0 = 0; k0 < NN; k0 += 32) {
        float4 g0 = *(const float4*)(x + (b0 + xr) * NN + k0 + xc);
        float4 g1 = *(const float4*)(x + (b0 + xr + 32) * NN + k0 + xc);
        float4 w0 = *(const float4*)(Wt + (k0 + bk) * NN + i0 + bc);
        float4 w1 = *(const float4*)(Wt + (k0 + bk + 16) * NN + i0 + bc);
        *(float4*)&Xs[xr][xc]      = g0;
        *(float4*)&Xs[xr + 32][xc] = g1;
        *(float4*)&Bs[bk][bc]      = w0;
        *(float4*)&Bs[bk + 16][bc] = w1;
        __syncthreads();

#pragma unroll 8
        for (int k = 0; k < 32; ++k) {
            float4 bv = *(const float4*)&Bs[k][tx * 4];
            float x0 = Xs[ty * 4 + 0][k];
            float x1 = Xs[ty * 4 + 1][k];
            float x2 = Xs[ty * 4 + 2][k];
            float x3 = Xs[ty * 4 + 3][k];
            acc[0][0] += x0 * bv.x; acc[0][1] += x0 * bv.y; acc[0][2] += x0 * bv.z; acc[0][3] += x0 * bv.w;
            acc[1][0] += x1 * bv.x; acc[1][1] += x1 * bv.y; acc[1][2] += x1 * bv.z; acc[1][3] += x1 * bv.w;
            acc[2][0] += x2 * bv.x; acc[2][1] += x2 * bv.y; acc[2][2] += x2 * bv.z; acc[2][3] += x2 * bv.w;
            acc[3][0] += x3 * bv.x; acc[3][1] += x3 * bv.y; acc[3][2] += x3 * bv.z; acc[3][3] += x3 * bv.w;
        }
        __syncthreads();
    }

#pragma unroll
    for (int mm = 0; mm < 4; ++mm) {
        *(float4*)(out + (b0 + ty * 4 + mm) * NN + i0 + tx * 4) =
            make_float4(acc[mm][0], acc[mm][1], acc[mm][2], acc[mm][3]);
    }
}

extern "C" void kernel_launch(void* const* d_in, const int* in_sizes, int n_in,
                              void* d_out, int out_size, void* d_ws, size_t ws_size,
                              hipStream_t stream) {
    const float* x     = (const float*)d_in[0];
    const float* theta = (const float*)d_in[1];
    const float* phi_i = (const float*)d_in[2];
    const float* phi_e = (const float*)d_in[3];
    float* out = (float*)d_out;

    f32x4*  cf3 = (f32x4*)d_ws;
    float2* A   = (float2*)((char*)d_ws + WS_A_OFF);
    float2* B   = (float2*)((char*)d_ws + WS_B_OFF);
    float*  Wt  = (float*)((char*)d_ws + WS_WT_OFF);

    coeff2_kernel<<<dim3(512), dim3(64), 0, stream>>>(theta, phi_i, cf3);
    build_kernel<<<dim3(32, 2), dim3(512), 0, stream>>>(cf3, A, B);
    merge_kernel<<<dim3(16, 16), dim3(256), 0, stream>>>(A, B, phi_e, Wt);
    gemm_kernel<<<dim3(NB / 64, NN / 64), dim3(256), 0, stream>>>(x, Wt, out);
}

// Round 10
// 72.742 us; speedup vs baseline: 1.0308x; 1.0308x over previous
//
#include <hip/hip_runtime.h>

// Reck-mesh MZI layer, N=256, BATCH=4096.
// out[b][i] = sum_j x[b][j] * Re(e^{i phi_ext[i]} U[i][j])
// Depth-split: U = A * B (steps 256..511 / 0..255), 512 independent half-depth
// column chains (wavefront t = 2L+p, disjoint row pairs per step).
// build: 2 waves/block x 256 blocks; both waves compute one column each and
// stage half the ring slots (global->reg->ds_write). Ring K=4, softbar
// (lgkmcnt-only s_barrier) per interval; global loads uncounted across it.
// Outputs stored TRANSPOSED (At[c][r]=A[r][c]) for coalesced stores + merge.
// merge: Wt[j][i] = Re(e^{i phi_i} sum_k At[k][i]*Bt[j][k]) — 2x2-blocked
// complex GEMM. Then real GEMM out = x @ Wt.

#define NN 256
#define NB 4096

typedef float f32x4 __attribute__((ext_vector_type(4)));

// ws layout:
//  [0, 1MB)       cf3: 64 groups x 16 slots x 64 lanes x 16B
//  [1MB, 1.5MB)   At  float2[256][256]  (At[c][r] = A[r][c], steps 256..511)
//  [1.5MB, 2MB)   Bt  float2[256][256]  (Bt[c][r] = B[r][c], steps 0..255)
//  [2MB, 2.25MB)  Wt  float[256][256]   (Wt[j][i])
#define WS_A_OFF  (1u << 20)
#define WS_B_OFF  ((1u << 20) + (1u << 19))
#define WS_WT_OFF (1u << 21)

// ---------------- coefficient stream ----------------
// t = 8g + jj. slot A_jj = jj (p = 4l, +1 if t odd), slot B_jj = 8+jj (p = A+2).
// Identity (1,0,0) baked in for inactive ops (incl. pad steps t=509..511).
__global__ __launch_bounds__(64) void coeff2_kernel(const float* __restrict__ theta,
                                                    const float* __restrict__ phi,
                                                    f32x4* __restrict__ cf3) {
    const int t = blockIdx.x;        // 0..511
    const int l = threadIdx.x;
    const int g = t >> 3, jj = t & 7;
    const int pA = (t & 1) ? (4 * l + 1) : (4 * l);
#pragma unroll
    for (int s = 0; s < 2; ++s) {
        int p = pA + 2 * s;
        f32x4 v = {1.f, 0.f, 0.f, 0.f};              // identity rotation
        if (p <= t && p + t <= 508) {                // active op at (t,p)
            int L = (t - p) >> 1;                    // layer 0..254
            int k = ((L * (511 - L)) >> 1) + p;      // off(L) = L*(511-L)/2
            float st, ct, sp, cp;
            __sincosf(theta[k], &st, &ct);
            __sincosf(phi[k], &sp, &cp);
            v = (f32x4){ct, st * cp, st * sp, 0.f};
        }
        cf3[(g * 16 + 8 * s + jj) * 64 + l] = v;
    }
}

// ---------------- build A/B columns ----------------
__device__ __forceinline__ float dpp_up1(float x) {   // lane i <- lane i-1, lane0 -> 0
    int r = __builtin_amdgcn_update_dpp(0, __builtin_bit_cast(int, x), 0x138, 0xF, 0xF, true);
    return __builtin_bit_cast(float, r);
}
__device__ __forceinline__ float dpp_dn1(float x) {   // lane i <- lane i+1, lane63 -> 0
    int r = __builtin_amdgcn_update_dpp(0, __builtin_bit_cast(int, x), 0x130, 0xF, 0xF, true);
    return __builtin_bit_cast(float, r);
}

__device__ __forceinline__ void rot2(float& ar, float& ai, float& br, float& bi, f32x4 co) {
    float c = co.x, sx = co.y, sy = co.z;
    float nar = c * ar - (sx * br + sy * bi);
    float nai = c * ai - (sx * bi - sy * br);
    float nbr = sx * ar - sy * ai + c * br;
    float nbi = sx * ai + sy * ar + c * bi;
    ar = nar; ai = nai; br = nbr; bi = nbi;
}

// LDS-only barrier: drain LDS ops; global loads may stay in flight.
__device__ __forceinline__ void softbar() {
    __builtin_amdgcn_sched_barrier(0);
    asm volatile("s_waitcnt lgkmcnt(0)" ::: "memory");
    __builtin_amdgcn_s_barrier();
    __builtin_amdgcn_sched_barrier(0);
}

__global__ __launch_bounds__(128, 1) void build_kernel(const f32x4* __restrict__ cf3,
                                                       float2* __restrict__ Ata,
                                                       float2* __restrict__ Btb) {
    // ring: 4 groups x 16 slots x 64 lanes x 16B = 65,536 B
    __shared__ f32x4 ring[4 * 16 * 64];

    const int tid = threadIdx.x;
    const int wid = tid >> 6;            // 0 or 1: column-wave index
    const int l   = tid & 63;
    const int r0  = 4 * l;
    const int j   = blockIdx.x * 2 + wid;   // column of the half-product
    const int h   = blockIdx.y;             // 0: steps 0..255 (B), 1: 256..511 (A)
    const int G0  = 32 * h;
    float2* dst = (h ? Ata : Btb) + (size_t)j * NN;   // row j of transposed half

    // state: rows 4l..4l+3 of column j, initialized to identity column
    float ur0 = (r0 + 0 == j) ? 1.f : 0.f, ui0 = 0.f;
    float ur1 = (r0 + 1 == j) ? 1.f : 0.f, ui1 = 0.f;
    float ur2 = (r0 + 2 == j) ? 1.f : 0.f, ui2 = 0.f;
    float ur3 = (r0 + 3 == j) ? 1.f : 0.f, ui3 = 0.f;
    const float lane0_one = (l == 0) ? 1.f : 0.f;   // C.x identity fix at lane 0

    f32x4 SA[8], SB[8];     // staging ping-pong: this wave's 8 slots
    f32x4 RA[16], RB[16];   // consume ping-pong

    auto loadown = [&](int g, f32x4 (&S)[8]) {       // global -> reg (own half)
        const f32x4* sp = cf3 + (size_t)g * 1024 + 8 * 64 * wid + l;
#pragma unroll
        for (int s = 0; s < 8; ++s) S[s] = sp[s * 64];
    };
    auto writeown = [&](int slot, const f32x4 (&S)[8]) {   // reg -> LDS (own half)
        f32x4* dp = ring + slot * 1024 + 8 * 64 * wid + l;
#pragma unroll
        for (int s = 0; s < 8; ++s) dp[s * 64] = S[s];
    };
    auto readslot = [&](int slot, f32x4 (&R)[16]) {        // LDS -> reg (all 16)
        const f32x4* rp = ring + slot * 1024 + l;
#pragma unroll
        for (int s = 0; s < 16; ++s) R[s] = rp[s * 64];
    };

    auto compute = [&](const f32x4 (&R)[16]) {       // 8 steps, VALU+DPP only
#pragma unroll
        for (int jj = 0; jj < 8; ++jj) {
            if ((jj & 1) == 0) {
                rot2(ur0, ui0, ur1, ui1, R[jj]);        // p = 4l
                rot2(ur2, ui2, ur3, ui3, R[8 + jj]);    // p = 4l+2
            } else {
                float d0r = dpp_dn1(ur0), d0i = dpp_dn1(ui0);  // lane l+1 row 4l+4
                float u3r = dpp_up1(ur3), u3i = dpp_up1(ui3);  // lane l-1 row 4l-1
                f32x4 cb = R[8 + jj];
                float cx = dpp_up1(cb.x) + lane0_one;   // C = lane l-1's B (lane0: id)
                float cy = dpp_up1(cb.y);
                float cz = dpp_up1(cb.z);
                rot2(ur1, ui1, ur2, ui2, R[jj]);        // p = 4l+1
                // p = 4l+3 (upper half here; lane63's B is identity)
                float n3r = cb.x * ur3 - (cb.y * d0r + cb.z * d0i);
                float n3i = cb.x * ui3 - (cb.y * d0i - cb.z * d0r);
                // p = 4l-1 (lower half here; lane0's C is identity)
                float n0r = cy * u3r - cz * u3i + cx * ur0;
                float n0i = cy * u3i + cz * u3r + cx * ui0;
                ur3 = n3r; ui3 = n3i; ur0 = n0r; ui0 = n0i;
            }
        }
    };

    // prefill: stage groups 0,1 into slots 0,1; hold 2,3 in regs
    loadown(G0 + 0, SA);
    loadown(G0 + 1, SB);
    writeown(0, SA);
    loadown(G0 + 2, SA);
    writeown(1, SB);
    loadown(G0 + 3, SB);
    softbar();
    readslot(0, RA);

    // 32 intervals (unrolled x2 for static ping-pong)
    for (int t = 0; t < 32; t += 2) {
        // interval t: compute group t; read t+1; write own(t+2); load own(t+4)
        if (t + 2 < 32) writeown((t + 2) & 3, SA);   // SA loaded 2 intervals ago
        if (t + 4 < 32) loadown(G0 + t + 4, SA);     // refill after store
        if (t + 1 < 32) readslot((t + 1) & 3, RB);
        compute(RA);
        softbar();
        // interval t+1
        if (t + 3 < 32) writeown((t + 3) & 3, SB);
        if (t + 5 < 32) loadown(G0 + t + 5, SB);
        if (t + 2 < 32) readslot((t + 2) & 3, RA);
        compute(RB);
        softbar();
    }

    // store column j as row j of the transposed half: coalesced 32B/lane
    *(float4*)(dst + r0)     = make_float4(ur0, ui0, ur1, ui1);
    *(float4*)(dst + r0 + 2) = make_float4(ur2, ui2, ur3, ui3);
}

// ---------------- merge: Wt[j][i] = Re(e^{i phi_i} sum_k At[k][i] Bt[j][k]) --
// 32x32 output tile, grid 8x8, 256 thr; 2x2 cplx outputs/thread (8 acc chains).
__global__ __launch_bounds__(256) void merge_kernel(const float2* __restrict__ At,
                                                    const float2* __restrict__ Bt,
                                                    const float* __restrict__ phi_ext,
                                                    float* __restrict__ Wt) {
    __shared__ float2 Ats[32][36];   // [k][i], padded (+4) for bank spread
    __shared__ float2 Bts[32][36];   // [j][k], padded

    const int t  = threadIdx.x;
    const int i0 = blockIdx.x * 32;
    const int j0 = blockIdx.y * 32;
    const int ti = (t & 15) * 2;
    const int tj = (t >> 4) * 2;

    float sr00 = 0, si00 = 0, sr01 = 0, si01 = 0;
    float sr10 = 0, si10 = 0, sr11 = 0, si11 = 0;

    for (int kc = 0; kc < NN; kc += 32) {
#pragma unroll
        for (int rep = 0; rep < 2; ++rep) {
            int e  = t + rep * 256;      // 0..511
            int kk = e >> 4;             // 0..31
            int f4 = e & 15;             // 0..15
            float4 v = *(const float4*)(At + (size_t)(kc + kk) * NN + i0 + 2 * f4);
            Ats[kk][2 * f4]     = make_float2(v.x, v.y);
            Ats[kk][2 * f4 + 1] = make_float2(v.z, v.w);
            float4 w = *(const float4*)(Bt + (size_t)(j0 + kk) * NN + kc + 2 * f4);
            Bts[kk][2 * f4]     = make_float2(w.x, w.y);
            Bts[kk][2 * f4 + 1] = make_float2(w.z, w.w);
        }
        __syncthreads();
#pragma unroll 8
        for (int k = 0; k < 32; ++k) {
            float2 a0 = Ats[k][ti], a1 = Ats[k][ti + 1];
            float2 b0 = Bts[tj][k], b1 = Bts[tj + 1][k];
            sr00 += a0.x * b0.x - a0.y * b0.y;  si00 += a0.x * b0.y + a0.y * b0.x;
            sr01 += a1.x * b0.x - a1.y * b0.y;  si01 += a1.x * b0.y + a1.y * b0.x;
            sr10 += a0.x * b1.x - a0.y * b1.y;  si10 += a0.x * b1.y + a0.y * b1.x;
            sr11 += a1.x * b1.x - a1.y * b1.y;  si11 += a1.x * b1.y + a1.y * b1.x;
        }
        __syncthreads();
    }

    float sp0, cp0, sp1, cp1;
    __sincosf(phi_ext[i0 + ti],     &sp0, &cp0);
    __sincosf(phi_ext[i0 + ti + 1], &sp1, &cp1);
    *(float2*)(Wt + (size_t)(j0 + tj) * NN + i0 + ti) =
        make_float2(cp0 * sr00 - sp0 * si00, cp1 * sr01 - sp1 * si01);
    *(float2*)(Wt + (size_t)(j0 + tj + 1) * NN + i0 + ti) =
        make_float2(cp0 * sr10 - sp0 * si10, cp1 * sr11 - sp1 * si11);
}

// ---------------- out = x @ Wt (fp32; no fp32 MFMA on CDNA4) ----------------
__global__ __launch_bounds__(256) void gemm_kernel(const float* __restrict__ x,
                                                   const float* __restrict__ Wt,
                                                   float* __restrict__ out) {
    __shared__ float Xs[64][36];
    __shared__ float Bs[32][68];

    const int tid = threadIdx.x;
    const int b0 = blockIdx.x * 64;
    const int i0 = blockIdx.y * 64;
    const int tx = tid & 15;
    const int ty = tid >> 4;

    const int xr = tid >> 3;
    const int xc = (tid & 7) * 4;
    const int bk = tid >> 4;
    const int bc = (tid & 15) * 4;

    float acc[4][4] = {};

    for (int k0 = 0; k0 < NN; k0 += 32) {
        float4 g0 = *(const float4*)(x + (b0 + xr) * NN + k0 + xc);
        float4 g1 = *(const float4*)(x + (b0 + xr + 32) * NN + k0 + xc);
        float4 w0 = *(const float4*)(Wt + (k0 + bk) * NN + i0 + bc);
        float4 w1 = *(const float4*)(Wt + (k0 + bk + 16) * NN + i0 + bc);
        *(float4*)&Xs[xr][xc]      = g0;
        *(float4*)&Xs[xr + 32][xc] = g1;
        *(float4*)&Bs[bk][bc]      = w0;
        *(float4*)&Bs[bk + 16][bc] = w1;
        __syncthreads();

#pragma unroll 8
        for (int k = 0; k < 32; ++k) {
            float4 bv = *(const float4*)&Bs[k][tx * 4];
            float x0 = Xs[ty * 4 + 0][k];
            float x1 = Xs[ty * 4 + 1][k];
            float x2 = Xs[ty * 4 + 2][k];
            float x3 = Xs[ty * 4 + 3][k];
            acc[0][0] += x0 * bv.x; acc[0][1] += x0 * bv.y; acc[0][2] += x0 * bv.z; acc[0][3] += x0 * bv.w;
            acc[1][0] += x1 * bv.x; acc[1][1] += x1 * bv.y; acc[1][2] += x1 * bv.z; acc[1][3] += x1 * bv.w;
            acc[2][0] += x2 * bv.x; acc[2][1] += x2 * bv.y; acc[2][2] += x2 * bv.z; acc[2][3] += x2 * bv.w;
            acc[3][0] += x3 * bv.x; acc[3][1] += x3 * bv.y; acc[3][2] += x3 * bv.z; acc[3][3] += x3 * bv.w;
        }
        __syncthreads();
    }

#pragma unroll
    for (int mm = 0; mm < 4; ++mm) {
        *(float4*)(out + (b0 + ty * 4 + mm) * NN + i0 + tx * 4) =
            make_float4(acc[mm][0], acc[mm][1], acc[mm][2], acc[mm][3]);
    }
}

extern "C" void kernel_launch(void* const* d_in, const int* in_sizes, int n_in,
                              void* d_out, int out_size, void* d_ws, size_t ws_size,
                              hipStream_t stream) {
    const float* x     = (const float*)d_in[0];
    const float* theta = (const float*)d_in[1];
    const float* phi_i = (const float*)d_in[2];
    const float* phi_e = (const float*)d_in[3];
    float* out = (float*)d_out;

    f32x4*  cf3 = (f32x4*)d_ws;
    float2* At  = (float2*)((char*)d_ws + WS_A_OFF);
    float2* Bt  = (float2*)((char*)d_ws + WS_B_OFF);
    float*  Wt  = (float*)((char*)d_ws + WS_WT_OFF);

    coeff2_kernel<<<dim3(512), dim3(64), 0, stream>>>(theta, phi_i, cf3);
    build_kernel<<<dim3(128, 2), dim3(128), 0, stream>>>(cf3, At, Bt);
    merge_kernel<<<dim3(8, 8), dim3(256), 0, stream>>>(At, Bt, phi_e, Wt);
    gemm_kernel<<<dim3(NB / 64, NN / 64), dim3(256), 0, stream>>>(x, Wt, out);
}

// Round 12
// 69.309 us; speedup vs baseline: 1.0818x; 1.0495x over previous
//
#include <hip/hip_runtime.h>

// Reck-mesh MZI layer, N=256, BATCH=4096.
// out[b][i] = sum_j x[b][j] * Re(e^{i phi_ext[i]} U[i][j])
// Depth-split: U = A * B (steps 256..511 / 0..255), 512 independent half-depth
// column chains (wavefront t = 2L+p). build: 2 waves/block x 256 blocks (R10,
// unchanged). merge: 2x2-blocked complex GEMM -> bf16 W[i][j] (j contiguous).
// gemm: bf16 MFMA 16x16x32, 64x64 tile, 4 waves, out = xb @ W^T.
// R12 fix: xb_kernel store index was gid*2 (32B stride for a 16B payload) ->
// half of xb stayed 0xAA-poisoned. Now xb4[gid].

#define NN 256
#define NB 4096

typedef float f32x4 __attribute__((ext_vector_type(4)));
typedef short bf16x8 __attribute__((ext_vector_type(8)));

// ws layout:
//  [0, 1MB)            cf3: 64 groups x 16 slots x 64 lanes x 16B
//  [1MB, 1.5MB)        At  float2[256][256]  (At[c][r] = A[r][c])
//  [1.5MB, 2MB)        Bt  float2[256][256]
//  [2MB, 2MB+128KB)    Wb  bf16[256][256]    (Wb[i][j], j contiguous)
//  [4MB, 6MB)          xb  bf16[4096][256]
#define WS_A_OFF  (1u << 20)
#define WS_B_OFF  ((1u << 20) + (1u << 19))
#define WS_WB_OFF (1u << 21)
#define WS_XB_OFF (1u << 22)

__device__ __forceinline__ unsigned short f2bf(float f) {   // RNE float->bf16
    unsigned u = __builtin_bit_cast(unsigned, f);
    unsigned r = (u + 0x7FFFu + ((u >> 16) & 1u)) >> 16;
    return (unsigned short)r;
}

// ---------------- coefficient stream (unchanged) ----------------
__global__ __launch_bounds__(64) void coeff2_kernel(const float* __restrict__ theta,
                                                    const float* __restrict__ phi,
                                                    f32x4* __restrict__ cf3) {
    const int t = blockIdx.x;        // 0..511
    const int l = threadIdx.x;
    const int g = t >> 3, jj = t & 7;
    const int pA = (t & 1) ? (4 * l + 1) : (4 * l);
#pragma unroll
    for (int s = 0; s < 2; ++s) {
        int p = pA + 2 * s;
        f32x4 v = {1.f, 0.f, 0.f, 0.f};              // identity rotation
        if (p <= t && p + t <= 508) {                // active op at (t,p)
            int L = (t - p) >> 1;                    // layer 0..254
            int k = ((L * (511 - L)) >> 1) + p;      // off(L) = L*(511-L)/2
            float st, ct, sp, cp;
            __sincosf(theta[k], &st, &ct);
            __sincosf(phi[k], &sp, &cp);
            v = (f32x4){ct, st * cp, st * sp, 0.f};
        }
        cf3[(g * 16 + 8 * s + jj) * 64 + l] = v;
    }
}

// ---------------- build A/B columns (unchanged R10) ----------------
__device__ __forceinline__ float dpp_up1(float x) {
    int r = __builtin_amdgcn_update_dpp(0, __builtin_bit_cast(int, x), 0x138, 0xF, 0xF, true);
    return __builtin_bit_cast(float, r);
}
__device__ __forceinline__ float dpp_dn1(float x) {
    int r = __builtin_amdgcn_update_dpp(0, __builtin_bit_cast(int, x), 0x130, 0xF, 0xF, true);
    return __builtin_bit_cast(float, r);
}

__device__ __forceinline__ void rot2(float& ar, float& ai, float& br, float& bi, f32x4 co) {
    float c = co.x, sx = co.y, sy = co.z;
    float nar = c * ar - (sx * br + sy * bi);
    float nai = c * ai - (sx * bi - sy * br);
    float nbr = sx * ar - sy * ai + c * br;
    float nbi = sx * ai + sy * ar + c * bi;
    ar = nar; ai = nai; br = nbr; bi = nbi;
}

__device__ __forceinline__ void softbar() {
    __builtin_amdgcn_sched_barrier(0);
    asm volatile("s_waitcnt lgkmcnt(0)" ::: "memory");
    __builtin_amdgcn_s_barrier();
    __builtin_amdgcn_sched_barrier(0);
}

__global__ __launch_bounds__(128, 1) void build_kernel(const f32x4* __restrict__ cf3,
                                                       float2* __restrict__ Ata,
                                                       float2* __restrict__ Btb) {
    __shared__ f32x4 ring[4 * 16 * 64];

    const int tid = threadIdx.x;
    const int wid = tid >> 6;
    const int l   = tid & 63;
    const int r0  = 4 * l;
    const int j   = blockIdx.x * 2 + wid;
    const int h   = blockIdx.y;
    const int G0  = 32 * h;
    float2* dst = (h ? Ata : Btb) + (size_t)j * NN;

    float ur0 = (r0 + 0 == j) ? 1.f : 0.f, ui0 = 0.f;
    float ur1 = (r0 + 1 == j) ? 1.f : 0.f, ui1 = 0.f;
    float ur2 = (r0 + 2 == j) ? 1.f : 0.f, ui2 = 0.f;
    float ur3 = (r0 + 3 == j) ? 1.f : 0.f, ui3 = 0.f;
    const float lane0_one = (l == 0) ? 1.f : 0.f;

    f32x4 SA[8], SB[8];
    f32x4 RA[16], RB[16];

    auto loadown = [&](int g, f32x4 (&S)[8]) {
        const f32x4* sp = cf3 + (size_t)g * 1024 + 8 * 64 * wid + l;
#pragma unroll
        for (int s = 0; s < 8; ++s) S[s] = sp[s * 64];
    };
    auto writeown = [&](int slot, const f32x4 (&S)[8]) {
        f32x4* dp = ring + slot * 1024 + 8 * 64 * wid + l;
#pragma unroll
        for (int s = 0; s < 8; ++s) dp[s * 64] = S[s];
    };
    auto readslot = [&](int slot, f32x4 (&R)[16]) {
        const f32x4* rp = ring + slot * 1024 + l;
#pragma unroll
        for (int s = 0; s < 16; ++s) R[s] = rp[s * 64];
    };

    auto compute = [&](const f32x4 (&R)[16]) {
#pragma unroll
        for (int jj = 0; jj < 8; ++jj) {
            if ((jj & 1) == 0) {
                rot2(ur0, ui0, ur1, ui1, R[jj]);
                rot2(ur2, ui2, ur3, ui3, R[8 + jj]);
            } else {
                float d0r = dpp_dn1(ur0), d0i = dpp_dn1(ui0);
                float u3r = dpp_up1(ur3), u3i = dpp_up1(ui3);
                f32x4 cb = R[8 + jj];
                float cx = dpp_up1(cb.x) + lane0_one;
                float cy = dpp_up1(cb.y);
                float cz = dpp_up1(cb.z);
                rot2(ur1, ui1, ur2, ui2, R[jj]);
                float n3r = cb.x * ur3 - (cb.y * d0r + cb.z * d0i);
                float n3i = cb.x * ui3 - (cb.y * d0i - cb.z * d0r);
                float n0r = cy * u3r - cz * u3i + cx * ur0;
                float n0i = cy * u3i + cz * u3r + cx * ui0;
                ur3 = n3r; ui3 = n3i; ur0 = n0r; ui0 = n0i;
            }
        }
    };

    loadown(G0 + 0, SA);
    loadown(G0 + 1, SB);
    writeown(0, SA);
    loadown(G0 + 2, SA);
    writeown(1, SB);
    loadown(G0 + 3, SB);
    softbar();
    readslot(0, RA);

    for (int t = 0; t < 32; t += 2) {
        if (t + 2 < 32) writeown((t + 2) & 3, SA);
        if (t + 4 < 32) loadown(G0 + t + 4, SA);
        if (t + 1 < 32) readslot((t + 1) & 3, RB);
        compute(RA);
        softbar();
        if (t + 3 < 32) writeown((t + 3) & 3, SB);
        if (t + 5 < 32) loadown(G0 + t + 5, SB);
        if (t + 2 < 32) readslot((t + 2) & 3, RA);
        compute(RB);
        softbar();
    }

    *(float4*)(dst + r0)     = make_float4(ur0, ui0, ur1, ui1);
    *(float4*)(dst + r0 + 2) = make_float4(ur2, ui2, ur3, ui3);
}

// ---------------- merge: Wb[i][j] = bf16(Re(e^{i phi_i} sum_k At[k][i] Bt[j][k]))
__global__ __launch_bounds__(256) void merge_kernel(const float2* __restrict__ At,
                                                    const float2* __restrict__ Bt,
                                                    const float* __restrict__ phi_ext,
                                                    unsigned short* __restrict__ Wb) {
    __shared__ float2 Ats[32][36];
    __shared__ float2 Bts[32][36];

    const int t  = threadIdx.x;
    const int i0 = blockIdx.x * 32;
    const int j0 = blockIdx.y * 32;
    const int ti = (t & 15) * 2;
    const int tj = (t >> 4) * 2;

    float sr00 = 0, si00 = 0, sr01 = 0, si01 = 0;
    float sr10 = 0, si10 = 0, sr11 = 0, si11 = 0;

    for (int kc = 0; kc < NN; kc += 32) {
#pragma unroll
        for (int rep = 0; rep < 2; ++rep) {
            int e  = t + rep * 256;
            int kk = e >> 4;
            int f4 = e & 15;
            float4 v = *(const float4*)(At + (size_t)(kc + kk) * NN + i0 + 2 * f4);
            Ats[kk][2 * f4]     = make_float2(v.x, v.y);
            Ats[kk][2 * f4 + 1] = make_float2(v.z, v.w);
            float4 w = *(const float4*)(Bt + (size_t)(j0 + kk) * NN + kc + 2 * f4);
            Bts[kk][2 * f4]     = make_float2(w.x, w.y);
            Bts[kk][2 * f4 + 1] = make_float2(w.z, w.w);
        }
        __syncthreads();
#pragma unroll 8
        for (int k = 0; k < 32; ++k) {
            float2 a0 = Ats[k][ti], a1 = Ats[k][ti + 1];
            float2 b0 = Bts[tj][k], b1 = Bts[tj + 1][k];
            sr00 += a0.x * b0.x - a0.y * b0.y;  si00 += a0.x * b0.y + a0.y * b0.x;
            sr01 += a1.x * b0.x - a1.y * b0.y;  si01 += a1.x * b0.y + a1.y * b0.x;
            sr10 += a0.x * b1.x - a0.y * b1.y;  si10 += a0.x * b1.y + a0.y * b1.x;
            sr11 += a1.x * b1.x - a1.y * b1.y;  si11 += a1.x * b1.y + a1.y * b1.x;
        }
        __syncthreads();
    }

    float sp0, cp0, sp1, cp1;
    __sincosf(phi_ext[i0 + ti],     &sp0, &cp0);
    __sincosf(phi_ext[i0 + ti + 1], &sp1, &cp1);
    // sr00=(i,j), sr01=(i+1,j), sr10=(i,j+1), sr11=(i+1,j+1); phase depends on i
    ushort2 lo = make_ushort2(f2bf(cp0 * sr00 - sp0 * si00), f2bf(cp0 * sr10 - sp0 * si10));
    ushort2 hi = make_ushort2(f2bf(cp1 * sr01 - sp1 * si01), f2bf(cp1 * sr11 - sp1 * si11));
    *(ushort2*)(Wb + (size_t)(i0 + ti) * NN + j0 + tj)     = lo;
    *(ushort2*)(Wb + (size_t)(i0 + ti + 1) * NN + j0 + tj) = hi;
}

// ---------------- xb = bf16(x) ----------------
__global__ __launch_bounds__(256) void xb_kernel(const float* __restrict__ x,
                                                 uint4* __restrict__ xb4) {
    int gid = blockIdx.x * 256 + threadIdx.x;        // 8 floats -> 16B of bf16
    const float4 v0 = ((const float4*)x)[gid * 2];
    const float4 v1 = ((const float4*)x)[gid * 2 + 1];
    uint4 w;
    w.x = (unsigned)f2bf(v0.x) | ((unsigned)f2bf(v0.y) << 16);
    w.y = (unsigned)f2bf(v0.z) | ((unsigned)f2bf(v0.w) << 16);
    w.z = (unsigned)f2bf(v1.x) | ((unsigned)f2bf(v1.y) << 16);
    w.w = (unsigned)f2bf(v1.z) | ((unsigned)f2bf(v1.w) << 16);
    xb4[gid] = w;                                    // same logical offset (R11 bug fix)
}

// ---------------- out = xb @ Wb^T via MFMA bf16 ----------------
// A = xb [4096][256] (m,k), B = Wb [256][256] (n,k). Tile 64m x 64n, BK=64.
// 4 waves: wave (wm,wn) owns 32x32 (2x2 16x16 frags).
__global__ __launch_bounds__(256) void gemm_kernel(const unsigned short* __restrict__ xb,
                                                   const unsigned short* __restrict__ Wb,
                                                   float* __restrict__ out) {
    __shared__ unsigned short Xs[64][72];   // 144B rows: conflict-light b128 frags
    __shared__ unsigned short Ws[64][72];

    const int tid = threadIdx.x;
    const int l   = tid & 63;
    const int wid = tid >> 6;
    const int wm  = wid >> 1, wn = wid & 1;
    const int b0  = blockIdx.x * 64;
    const int i0  = blockIdx.y * 64;

    const int srow = tid >> 2;            // staging: row 0..63
    const int sseg = (tid & 3) * 2;       // 2 of 8 8-elem segments

    f32x4 acc[2][2] = {{{0.f, 0.f, 0.f, 0.f}, {0.f, 0.f, 0.f, 0.f}},
                       {{0.f, 0.f, 0.f, 0.f}, {0.f, 0.f, 0.f, 0.f}}};

    const int fr = l & 15;        // fragment row (m or n)
    const int kg = (l >> 4) * 8;  // fragment k-group base (8 contiguous)

    for (int k0 = 0; k0 < NN; k0 += 64) {
        uint4 xv  = *(const uint4*)(xb + (size_t)(b0 + srow) * NN + k0 + sseg * 8);
        uint4 wv  = *(const uint4*)(Wb + (size_t)(i0 + srow) * NN + k0 + sseg * 8);
        uint4 xv2 = *(const uint4*)(xb + (size_t)(b0 + srow) * NN + k0 + (sseg + 1) * 8);
        uint4 wv2 = *(const uint4*)(Wb + (size_t)(i0 + srow) * NN + k0 + (sseg + 1) * 8);
        *(uint4*)&Xs[srow][sseg * 8]       = xv;
        *(uint4*)&Ws[srow][sseg * 8]       = wv;
        *(uint4*)&Xs[srow][(sseg + 1) * 8] = xv2;
        *(uint4*)&Ws[srow][(sseg + 1) * 8] = wv2;
        __syncthreads();

#pragma unroll
        for (int ks = 0; ks < 2; ++ks) {
            bf16x8 a0  = *(const bf16x8*)&Xs[wm * 32 + fr][ks * 32 + kg];
            bf16x8 a1  = *(const bf16x8*)&Xs[wm * 32 + 16 + fr][ks * 32 + kg];
            bf16x8 bb0 = *(const bf16x8*)&Ws[wn * 32 + fr][ks * 32 + kg];
            bf16x8 bb1 = *(const bf16x8*)&Ws[wn * 32 + 16 + fr][ks * 32 + kg];
            acc[0][0] = __builtin_amdgcn_mfma_f32_16x16x32_bf16(a0, bb0, acc[0][0], 0, 0, 0);
            acc[0][1] = __builtin_amdgcn_mfma_f32_16x16x32_bf16(a0, bb1, acc[0][1], 0, 0, 0);
            acc[1][0] = __builtin_amdgcn_mfma_f32_16x16x32_bf16(a1, bb0, acc[1][0], 0, 0, 0);
            acc[1][1] = __builtin_amdgcn_mfma_f32_16x16x32_bf16(a1, bb1, acc[1][1], 0, 0, 0);
        }
        __syncthreads();
    }

    // D layout: col = l&15, row = (l>>4)*4 + reg   [m89-verified]
    const int drow = (l >> 4) * 4;
    const int dcol = l & 15;
#pragma unroll
    for (int mf = 0; mf < 2; ++mf)
#pragma unroll
        for (int nf = 0; nf < 2; ++nf) {
            float* op = out + (size_t)(b0 + wm * 32 + mf * 16 + drow) * NN
                      + i0 + wn * 32 + nf * 16 + dcol;
#pragma unroll
            for (int r = 0; r < 4; ++r) op[(size_t)r * NN] = acc[mf][nf][r];
        }
}

extern "C" void kernel_launch(void* const* d_in, const int* in_sizes, int n_in,
                              void* d_out, int out_size, void* d_ws, size_t ws_size,
                              hipStream_t stream) {
    const float* x     = (const float*)d_in[0];
    const float* theta = (const float*)d_in[1];
    const float* phi_i = (const float*)d_in[2];
    const float* phi_e = (const float*)d_in[3];
    float* out = (float*)d_out;

    f32x4*  cf3 = (f32x4*)d_ws;
    float2* At  = (float2*)((char*)d_ws + WS_A_OFF);
    float2* Bt  = (float2*)((char*)d_ws + WS_B_OFF);
    unsigned short* Wb = (unsigned short*)((char*)d_ws + WS_WB_OFF);
    unsigned short* xb = (unsigned short*)((char*)d_ws + WS_XB_OFF);

    coeff2_kernel<<<dim3(512), dim3(64), 0, stream>>>(theta, phi_i, cf3);
    build_kernel<<<dim3(128, 2), dim3(128), 0, stream>>>(cf3, At, Bt);
    xb_kernel<<<dim3(NB * NN / (256 * 8)), dim3(256), 0, stream>>>(x, (uint4*)xb);
    merge_kernel<<<dim3(8, 8), dim3(256), 0, stream>>>(At, Bt, phi_e, Wb);
    gemm_kernel<<<dim3(NB / 64, NN / 64), dim3(256), 0, stream>>>(xb, Wb, out);
}

// Round 13
// 48.088 us; speedup vs baseline: 1.5592x; 1.4413x over previous
//
#include <hip/hip_runtime.h>

// Reck-mesh MZI layer, N=256, BATCH=4096.
// out[b][i] = sum_j x[b][j] * Re(e^{i phi_ext[i]} U[i][j])
// Depth-split: U = A * B (steps 256..511 / 0..255), 512 independent half-depth
// column chains (wavefront t = 2L+p, disjoint row pairs per step).
// build (R13): ONE WAVE PER CHAIN, register-only double-buffer. Loads for
// group g+1 are pinned early by an asm memory fence (no LDS, no barriers);
// compiler emits counted vmcnt at first use. 512 single-wave blocks.
// merge: split-k x4 fp32 partials (256 blocks) + reduce (phase + bf16).
// gemm: bf16 MFMA 16x16x32, 64x64 tile, out = xb @ Wb^T.

#define NN 256
#define NB 4096

typedef float f32x4 __attribute__((ext_vector_type(4)));
typedef short bf16x8 __attribute__((ext_vector_type(8)));

// ws layout (<= 5.5MB, within proven budget):
//  [0, 512K)        At  float2[256][256]   (At[c][r] = A[r][c])
//  [512K, 1M)       Bt  float2[256][256]
//  [1M, 2M)         cf3: 64 groups x 16 slots x 64 lanes x 16B
//  [1M, 3M)         parts: 4 x float2[256][256]  (OVERLAYS cf3 — dead after build)
//  [3M, 3M+128K)    Wb  bf16[256][256]
//  [3.5M, 5.5M)     xb  bf16[4096][256]
#define WS_AT_OFF   0u
#define WS_BT_OFF   (512u * 1024u)
#define WS_CF_OFF   (1u << 20)
#define WS_PART_OFF (1u << 20)
#define WS_WB_OFF   (3u << 20)
#define WS_XB_OFF   ((3u << 20) + (1u << 19))

__device__ __forceinline__ unsigned short f2bf(float f) {   // RNE float->bf16
    unsigned u = __builtin_bit_cast(unsigned, f);
    unsigned r = (u + 0x7FFFu + ((u >> 16) & 1u)) >> 16;
    return (unsigned short)r;
}

// ---------------- coefficient stream (unchanged) ----------------
__global__ __launch_bounds__(64) void coeff2_kernel(const float* __restrict__ theta,
                                                    const float* __restrict__ phi,
                                                    f32x4* __restrict__ cf3) {
    const int t = blockIdx.x;        // 0..511
    const int l = threadIdx.x;
    const int g = t >> 3, jj = t & 7;
    const int pA = (t & 1) ? (4 * l + 1) : (4 * l);
#pragma unroll
    for (int s = 0; s < 2; ++s) {
        int p = pA + 2 * s;
        f32x4 v = {1.f, 0.f, 0.f, 0.f};              // identity rotation
        if (p <= t && p + t <= 508) {                // active op at (t,p)
            int L = (t - p) >> 1;                    // layer 0..254
            int k = ((L * (511 - L)) >> 1) + p;      // off(L) = L*(511-L)/2
            float st, ct, sp, cp;
            __sincosf(theta[k], &st, &ct);
            __sincosf(phi[k], &sp, &cp);
            v = (f32x4){ct, st * cp, st * sp, 0.f};
        }
        cf3[(g * 16 + 8 * s + jj) * 64 + l] = v;
    }
}

// ---------------- build A/B columns: 1 wave = 1 chain, reg-only ----------------
__device__ __forceinline__ float dpp_up1(float x) {   // lane i <- lane i-1, lane0 -> 0
    int r = __builtin_amdgcn_update_dpp(0, __builtin_bit_cast(int, x), 0x138, 0xF, 0xF, true);
    return __builtin_bit_cast(float, r);
}
__device__ __forceinline__ float dpp_dn1(float x) {   // lane i <- lane i+1, lane63 -> 0
    int r = __builtin_amdgcn_update_dpp(0, __builtin_bit_cast(int, x), 0x130, 0xF, 0xF, true);
    return __builtin_bit_cast(float, r);
}

__device__ __forceinline__ void rot2(float& ar, float& ai, float& br, float& bi, f32x4 co) {
    float c = co.x, sx = co.y, sy = co.z;
    float nar = c * ar - (sx * br + sy * bi);
    float nai = c * ai - (sx * bi - sy * br);
    float nbr = sx * ar - sy * ai + c * br;
    float nbi = sx * ai + sy * ar + c * bi;
    ar = nar; ai = nai; br = nbr; bi = nbi;
}

// compiler+scheduler fence: pins already-issued loads before it (a load cannot
// sink past an asm memory clobber), emits no instructions.
__device__ __forceinline__ void fence() {
    asm volatile("" ::: "memory");
    __builtin_amdgcn_sched_barrier(0);
}

__global__ __launch_bounds__(64, 1) void build_kernel(const f32x4* __restrict__ cf3,
                                                      float2* __restrict__ Ata,
                                                      float2* __restrict__ Btb) {
    const int l  = threadIdx.x;
    const int r0 = 4 * l;
    const int j  = blockIdx.x;           // column 0..255
    const int h  = blockIdx.y;           // 0: steps 0..255 (B), 1: 256..511 (A)
    const int G0 = 32 * h;
    float2* dst = (h ? Ata : Btb) + (size_t)j * NN;

    float ur0 = (r0 + 0 == j) ? 1.f : 0.f, ui0 = 0.f;
    float ur1 = (r0 + 1 == j) ? 1.f : 0.f, ui1 = 0.f;
    float ur2 = (r0 + 2 == j) ? 1.f : 0.f, ui2 = 0.f;
    float ur3 = (r0 + 3 == j) ? 1.f : 0.f, ui3 = 0.f;
    const float lane0_one = (l == 0) ? 1.f : 0.f;

    f32x4 RA[16], RB[16];    // register double-buffer (64 VGPR each)

    auto loadgrp = [&](int g, f32x4 (&R)[16]) {
        const f32x4* sp = cf3 + (size_t)g * 1024 + l;
#pragma unroll
        for (int s = 0; s < 16; ++s) R[s] = sp[s * 64];
    };

    auto compute = [&](const f32x4 (&R)[16]) {       // 8 steps, VALU+DPP only
#pragma unroll
        for (int jj = 0; jj < 8; ++jj) {
            if ((jj & 1) == 0) {
                rot2(ur0, ui0, ur1, ui1, R[jj]);        // p = 4l
                rot2(ur2, ui2, ur3, ui3, R[8 + jj]);    // p = 4l+2
            } else {
                float d0r = dpp_dn1(ur0), d0i = dpp_dn1(ui0);  // lane l+1 row 4l+4
                float u3r = dpp_up1(ur3), u3i = dpp_up1(ui3);  // lane l-1 row 4l-1
                f32x4 cb = R[8 + jj];
                float cx = dpp_up1(cb.x) + lane0_one;   // C = lane l-1's B (lane0: id)
                float cy = dpp_up1(cb.y);
                float cz = dpp_up1(cb.z);
                rot2(ur1, ui1, ur2, ui2, R[jj]);        // p = 4l+1
                float n3r = cb.x * ur3 - (cb.y * d0r + cb.z * d0i);   // p = 4l+3
                float n3i = cb.x * ui3 - (cb.y * d0i - cb.z * d0r);
                float n0r = cy * u3r - cz * u3i + cx * ur0;           // p = 4l-1
                float n0i = cy * u3i + cz * u3r + cx * ui0;
                ur3 = n3r; ui3 = n3i; ur0 = n0r; ui0 = n0i;
            }
        }
    };

    loadgrp(G0 + 0, RA);
    fence();
    for (int g = 0; g < 32; g += 2) {
        if (g + 1 < 32) loadgrp(G0 + g + 1, RB);   // in flight during compute(RA)
        fence();
        compute(RA);
        if (g + 2 < 32) loadgrp(G0 + g + 2, RA);
        fence();
        compute(RB);
    }

    // store column j as row j of the transposed half: coalesced 32B/lane
    *(float4*)(dst + r0)     = make_float4(ur0, ui0, ur1, ui1);
    *(float4*)(dst + r0 + 2) = make_float4(ur2, ui2, ur3, ui3);
}

// ---------------- merge part: partial_z[i][j] = sum_{k in chunk z} At[k][i]*Bt[j][k]
__global__ __launch_bounds__(256) void merge_part_kernel(const float2* __restrict__ At,
                                                         const float2* __restrict__ Bt,
                                                         float2* __restrict__ parts) {
    __shared__ float2 Ats[32][36];
    __shared__ float2 Bts[32][36];

    const int t  = threadIdx.x;
    const int i0 = blockIdx.x * 32;
    const int j0 = blockIdx.y * 32;
    const int kc0 = blockIdx.z * 64;
    const int ti = (t & 15) * 2;
    const int tj = (t >> 4) * 2;

    float sr00 = 0, si00 = 0, sr01 = 0, si01 = 0;
    float sr10 = 0, si10 = 0, sr11 = 0, si11 = 0;

    for (int kc = kc0; kc < kc0 + 64; kc += 32) {
#pragma unroll
        for (int rep = 0; rep < 2; ++rep) {
            int e  = t + rep * 256;
            int kk = e >> 4;
            int f4 = e & 15;
            float4 v = *(const float4*)(At + (size_t)(kc + kk) * NN + i0 + 2 * f4);
            Ats[kk][2 * f4]     = make_float2(v.x, v.y);
            Ats[kk][2 * f4 + 1] = make_float2(v.z, v.w);
            float4 w = *(const float4*)(Bt + (size_t)(j0 + kk) * NN + kc + 2 * f4);
            Bts[kk][2 * f4]     = make_float2(w.x, w.y);
            Bts[kk][2 * f4 + 1] = make_float2(w.z, w.w);
        }
        __syncthreads();
#pragma unroll 8
        for (int k = 0; k < 32; ++k) {
            float2 a0 = Ats[k][ti], a1 = Ats[k][ti + 1];
            float2 b0 = Bts[tj][k], b1 = Bts[tj + 1][k];
            sr00 += a0.x * b0.x - a0.y * b0.y;  si00 += a0.x * b0.y + a0.y * b0.x;
            sr01 += a1.x * b0.x - a1.y * b0.y;  si01 += a1.x * b0.y + a1.y * b0.x;
            sr10 += a0.x * b1.x - a0.y * b1.y;  si10 += a0.x * b1.y + a0.y * b1.x;
            sr11 += a1.x * b1.x - a1.y * b1.y;  si11 += a1.x * b1.y + a1.y * b1.x;
        }
        __syncthreads();
    }

    float2* p = parts + (size_t)blockIdx.z * (NN * NN);
    p[(size_t)(i0 + ti) * NN + j0 + tj]         = make_float2(sr00, si00);
    p[(size_t)(i0 + ti + 1) * NN + j0 + tj]     = make_float2(sr01, si01);
    p[(size_t)(i0 + ti) * NN + j0 + tj + 1]     = make_float2(sr10, si10);
    p[(size_t)(i0 + ti + 1) * NN + j0 + tj + 1] = make_float2(sr11, si11);
}

// ---------------- reduce: Wb[i][j] = bf16(cos(phi_i)*Re - sin(phi_i)*Im) ----
__global__ __launch_bounds__(256) void reduce_kernel(const float2* __restrict__ parts,
                                                     const float* __restrict__ phi_ext,
                                                     unsigned short* __restrict__ Wb) {
    int gid = blockIdx.x * 256 + threadIdx.x;   // 0..16383, 4 j's per thread
    int i  = gid >> 6;
    int j  = (gid & 63) * 4;
    float re0 = 0, im0 = 0, re1 = 0, im1 = 0, re2 = 0, im2 = 0, re3 = 0, im3 = 0;
#pragma unroll
    for (int z = 0; z < 4; ++z) {
        const float2* p = parts + (size_t)z * (NN * NN) + (size_t)i * NN + j;
        float4 a = *(const float4*)(p);
        float4 b = *(const float4*)(p + 2);
        re0 += a.x; im0 += a.y; re1 += a.z; im1 += a.w;
        re2 += b.x; im2 += b.y; re3 += b.z; im3 += b.w;
    }
    float sp, cp;
    __sincosf(phi_ext[i], &sp, &cp);
    ushort4 o;
    o.x = f2bf(cp * re0 - sp * im0);
    o.y = f2bf(cp * re1 - sp * im1);
    o.z = f2bf(cp * re2 - sp * im2);
    o.w = f2bf(cp * re3 - sp * im3);
    *(ushort4*)(Wb + (size_t)i * NN + j) = o;
}

// ---------------- xb = bf16(x) ----------------
__global__ __launch_bounds__(256) void xb_kernel(const float* __restrict__ x,
                                                 uint4* __restrict__ xb4) {
    int gid = blockIdx.x * 256 + threadIdx.x;        // 8 floats -> 16B of bf16
    const float4 v0 = ((const float4*)x)[gid * 2];
    const float4 v1 = ((const float4*)x)[gid * 2 + 1];
    uint4 w;
    w.x = (unsigned)f2bf(v0.x) | ((unsigned)f2bf(v0.y) << 16);
    w.y = (unsigned)f2bf(v0.z) | ((unsigned)f2bf(v0.w) << 16);
    w.z = (unsigned)f2bf(v1.x) | ((unsigned)f2bf(v1.y) << 16);
    w.w = (unsigned)f2bf(v1.z) | ((unsigned)f2bf(v1.w) << 16);
    xb4[gid] = w;
}

// ---------------- out = xb @ Wb^T via MFMA bf16 (unchanged R12) ----------------
__global__ __launch_bounds__(256) void gemm_kernel(const unsigned short* __restrict__ xb,
                                                   const unsigned short* __restrict__ Wb,
                                                   float* __restrict__ out) {
    __shared__ unsigned short Xs[64][72];
    __shared__ unsigned short Ws[64][72];

    const int tid = threadIdx.x;
    const int l   = tid & 63;
    const int wid = tid >> 6;
    const int wm  = wid >> 1, wn = wid & 1;
    const int b0  = blockIdx.x * 64;
    const int i0  = blockIdx.y * 64;

    const int srow = tid >> 2;
    const int sseg = (tid & 3) * 2;

    f32x4 acc[2][2] = {{{0.f, 0.f, 0.f, 0.f}, {0.f, 0.f, 0.f, 0.f}},
                       {{0.f, 0.f, 0.f, 0.f}, {0.f, 0.f, 0.f, 0.f}}};

    const int fr = l & 15;
    const int kg = (l >> 4) * 8;

    for (int k0 = 0; k0 < NN; k0 += 64) {
        uint4 xv  = *(const uint4*)(xb + (size_t)(b0 + srow) * NN + k0 + sseg * 8);
        uint4 wv  = *(const uint4*)(Wb + (size_t)(i0 + srow) * NN + k0 + sseg * 8);
        uint4 xv2 = *(const uint4*)(xb + (size_t)(b0 + srow) * NN + k0 + (sseg + 1) * 8);
        uint4 wv2 = *(const uint4*)(Wb + (size_t)(i0 + srow) * NN + k0 + (sseg + 1) * 8);
        *(uint4*)&Xs[srow][sseg * 8]       = xv;
        *(uint4*)&Ws[srow][sseg * 8]       = wv;
        *(uint4*)&Xs[srow][(sseg + 1) * 8] = xv2;
        *(uint4*)&Ws[srow][(sseg + 1) * 8] = wv2;
        __syncthreads();

#pragma unroll
        for (int ks = 0; ks < 2; ++ks) {
            bf16x8 a0  = *(const bf16x8*)&Xs[wm * 32 + fr][ks * 32 + kg];
            bf16x8 a1  = *(const bf16x8*)&Xs[wm * 32 + 16 + fr][ks * 32 + kg];
            bf16x8 bb0 = *(const bf16x8*)&Ws[wn * 32 + fr][ks * 32 + kg];
            bf16x8 bb1 = *(const bf16x8*)&Ws[wn * 32 + 16 + fr][ks * 32 + kg];
            acc[0][0] = __builtin_amdgcn_mfma_f32_16x16x32_bf16(a0, bb0, acc[0][0], 0, 0, 0);
            acc[0][1] = __builtin_amdgcn_mfma_f32_16x16x32_bf16(a0, bb1, acc[0][1], 0, 0, 0);
            acc[1][0] = __builtin_amdgcn_mfma_f32_16x16x32_bf16(a1, bb0, acc[1][0], 0, 0, 0);
            acc[1][1] = __builtin_amdgcn_mfma_f32_16x16x32_bf16(a1, bb1, acc[1][1], 0, 0, 0);
        }
        __syncthreads();
    }

    const int drow = (l >> 4) * 4;
    const int dcol = l & 15;
#pragma unroll
    for (int mf = 0; mf < 2; ++mf)
#pragma unroll
        for (int nf = 0; nf < 2; ++nf) {
            float* op = out + (size_t)(b0 + wm * 32 + mf * 16 + drow) * NN
                      + i0 + wn * 32 + nf * 16 + dcol;
#pragma unroll
            for (int r = 0; r < 4; ++r) op[(size_t)r * NN] = acc[mf][nf][r];
        }
}

extern "C" void kernel_launch(void* const* d_in, const int* in_sizes, int n_in,
                              void* d_out, int out_size, void* d_ws, size_t ws_size,
                              hipStream_t stream) {
    const float* x     = (const float*)d_in[0];
    const float* theta = (const float*)d_in[1];
    const float* phi_i = (const float*)d_in[2];
    const float* phi_e = (const float*)d_in[3];
    float* out = (float*)d_out;

    float2* At    = (float2*)((char*)d_ws + WS_AT_OFF);
    float2* Bt    = (float2*)((char*)d_ws + WS_BT_OFF);
    f32x4*  cf3   = (f32x4*)((char*)d_ws + WS_CF_OFF);
    float2* parts = (float2*)((char*)d_ws + WS_PART_OFF);   // overlays cf3 (dead)
    unsigned short* Wb = (unsigned short*)((char*)d_ws + WS_WB_OFF);
    unsigned short* xb = (unsigned short*)((char*)d_ws + WS_XB_OFF);

    coeff2_kernel<<<dim3(512), dim3(64), 0, stream>>>(theta, phi_i, cf3);
    build_kernel<<<dim3(256, 2), dim3(64), 0, stream>>>(cf3, At, Bt);
    xb_kernel<<<dim3(NB * NN / (256 * 8)), dim3(256), 0, stream>>>(x, (uint4*)xb);
    merge_part_kernel<<<dim3(8, 8, 4), dim3(256), 0, stream>>>(At, Bt, parts);
    reduce_kernel<<<dim3(64), dim3(256), 0, stream>>>(parts, phi_e, Wb);
    gemm_kernel<<<dim3(NB / 64, NN / 64), dim3(256), 0, stream>>>(xb, Wb, out);
}